// Round 1
// baseline (1406.700 us; speedup 1.0000x reference)
//
#include <hip/hip_runtime.h>
#include <hip/hip_bf16.h>
#include <math.h>

#define NTOK 8192
#define DM 512
#define DFF 2048
#define NE 8

typedef __attribute__((ext_vector_type(8))) short bfrag;     // 8 bf16 (4 VGPRs)
typedef __attribute__((ext_vector_type(4))) float f32x4;
typedef __attribute__((ext_vector_type(4))) unsigned int u32x4;
typedef __attribute__((ext_vector_type(4))) short s16x4;

__device__ __forceinline__ short f2bf(float f) {
  unsigned u = __builtin_bit_cast(unsigned, f);
  u += 0x7fffu + ((u >> 16) & 1u);   // round-to-nearest-even
  return (short)(u >> 16);
}

// ---------------- fp32 -> bf16 conversion (vectorized x4) ----------------
__global__ __launch_bounds__(256) void cvt_kernel(const float* __restrict__ in,
                                                  short* __restrict__ o, int n4) {
  int i = blockIdx.x * 256 + threadIdx.x;
  if (i >= n4) return;
  f32x4 v = ((const f32x4*)in)[i];
  s16x4 s;
  #pragma unroll
  for (int j = 0; j < 4; j++) s[j] = f2bf(v[j]);
  ((s16x4*)o)[i] = s;
}

// ---------------- router: logits, softmax, top-p routing, aux stats ----------------
// 1 wave per token, 4 tokens per block.
__global__ __launch_bounds__(256) void router_kernel(const float* __restrict__ x,
                                                     const float* __restrict__ rw,
                                                     float* __restrict__ w_all,
                                                     float* __restrict__ stats) {
  __shared__ float s_cnt[NE], s_ps[NE];
  if (threadIdx.x < NE) { s_cnt[threadIdx.x] = 0.f; s_ps[threadIdx.x] = 0.f; }
  __syncthreads();
  int wave = threadIdx.x >> 6, lane = threadIdx.x & 63;
  int token = blockIdx.x * 4 + wave;
  const float* xt = x + (size_t)token * DM;
  float acc[NE];
  #pragma unroll
  for (int e = 0; e < NE; e++) acc[e] = 0.f;
  #pragma unroll
  for (int kk = 0; kk < DM / 64; kk++) {
    int k = kk * 64 + lane;
    float xv = xt[k];
    f32x4 r0 = *(const f32x4*)(rw + k * NE);
    f32x4 r1 = *(const f32x4*)(rw + k * NE + 4);
    acc[0] += xv * r0[0]; acc[1] += xv * r0[1]; acc[2] += xv * r0[2]; acc[3] += xv * r0[3];
    acc[4] += xv * r1[0]; acc[5] += xv * r1[1]; acc[6] += xv * r1[2]; acc[7] += xv * r1[3];
  }
  #pragma unroll
  for (int off = 32; off >= 1; off >>= 1) {
    #pragma unroll
    for (int e = 0; e < NE; e++) acc[e] += __shfl_xor(acc[e], off, 64);
  }
  // softmax (redundant on all lanes; cheap)
  float mx = acc[0];
  #pragma unroll
  for (int e = 1; e < NE; e++) mx = fmaxf(mx, acc[e]);
  float p[NE]; float sum = 0.f;
  #pragma unroll
  for (int e = 0; e < NE; e++) { p[e] = expf(acc[e] - mx); sum += p[e]; }
  float inv = 1.f / sum;
  #pragma unroll
  for (int e = 0; e < NE; e++) p[e] *= inv;
  // stable top-4 (ties -> lowest index, matches jax top_k)
  float sp[4]; int si[4]; unsigned used = 0;
  #pragma unroll
  for (int s = 0; s < 4; s++) {
    float bp = -1.f; int bi = 0;
    #pragma unroll
    for (int e = 0; e < NE; e++)
      if (!((used >> e) & 1u) && p[e] > bp) { bp = p[e]; bi = e; }
    used |= 1u << bi; sp[s] = bp; si[s] = bi;
  }
  // top-p keep: slot kept if s < MIN_EXPERTS or shifted-cumsum < 0.9
  float csum = 0.f, wsum = 0.f; bool keep[4];
  #pragma unroll
  for (int s = 0; s < 4; s++) {
    keep[s] = (s < 1) || (csum < 0.9f);
    csum += sp[s];
    if (keep[s]) wsum += sp[s];
  }
  wsum = fmaxf(wsum, 1e-9f);
  float we[NE];
  #pragma unroll
  for (int e = 0; e < NE; e++) we[e] = 0.f;
  #pragma unroll
  for (int s = 0; s < 4; s++) if (keep[s]) we[si[s]] = sp[s] / wsum;

  if (lane == 0) {
    #pragma unroll
    for (int e = 0; e < NE; e++) w_all[(size_t)token * NE + e] = we[e];
    #pragma unroll
    for (int e = 0; e < NE; e++) atomicAdd(&s_ps[e], p[e]);
    #pragma unroll
    for (int s = 0; s < 4; s++) if (keep[s]) atomicAdd(&s_cnt[si[s]], 1.f);
  }
  __syncthreads();
  if (threadIdx.x < NE) {
    atomicAdd(&stats[threadIdx.x], s_cnt[threadIdx.x]);
    atomicAdd(&stats[NE + threadIdx.x], s_ps[threadIdx.x]);
  }
}

// ---------------- aux loss finalize ----------------
__global__ void aux_kernel(const float* __restrict__ stats, float* __restrict__ auxp) {
  float tot = 0.f;
  for (int e = 0; e < NE; e++) tot += stats[e];
  float t = fmaxf(tot, 1.f);
  float s = 0.f;
  for (int e = 0; e < NE; e++) s += (stats[e] / t) * (stats[NE + e] / (float)NTOK);
  auxp[0] = 0.01f * (float)NE * s;
}

// ---------------- bf16 MFMA GEMM, 128x128 tile, BK=32 ----------------
// MODE 0: H = bf16(gelu_exact(A@B + bias))       (ldc = N = DFF)
// MODE 1: out += w_all[row][expert] * (A@B + bias)  (ldc = N = DM)
template <int MODE>
__global__ __launch_bounds__(256) void gemm_kernel(
    const short* __restrict__ A,   // bf16 M x K row-major
    const short* __restrict__ B,   // bf16 K x N row-major
    const float* __restrict__ bias,
    short* __restrict__ H, float* __restrict__ out, const float* __restrict__ w_all,
    int expert, int M, int N, int K) {
  __shared__ __align__(16) short As[128 * 40];  // [m][k], stride 40 (pad: 80B rows, 16B-aligned)
  __shared__ __align__(16) short Bs[128 * 40];  // [n][k] (transposed at stage time)
  int tid = threadIdx.x;
  int wave = tid >> 6, lane = tid & 63;
  int wm = wave >> 1, wn = wave & 1;
  int quad = lane >> 4, l16 = lane & 15;
  int m0 = blockIdx.x * 128, n0 = blockIdx.y * 128;

  f32x4 acc[4][4];
  #pragma unroll
  for (int i = 0; i < 4; i++)
    #pragma unroll
    for (int j = 0; j < 4; j++) acc[i][j] = (f32x4){0.f, 0.f, 0.f, 0.f};

  const short* Abase = A + (size_t)m0 * K;
  int bk = tid >> 3, bnseg = tid & 7;

  for (int kt = 0; kt < K; kt += 32) {
    // stage A: 128x32, 16B chunks
    #pragma unroll
    for (int h = 0; h < 2; h++) {
      int c = tid + h * 256;
      int row = c >> 2, seg = c & 3;
      u32x4 v = *(const u32x4*)(Abase + (size_t)row * K + kt + seg * 8);
      *(u32x4*)(As + row * 40 + seg * 8) = v;
    }
    // stage B transposed: each thread reads 16 contiguous bf16 of one k-row, scatters to [n][k]
    {
      const short* bp = B + (size_t)(kt + bk) * N + n0 + bnseg * 16;
      union { u32x4 v; short s[8]; } t0, t1;
      t0.v = *(const u32x4*)bp;
      t1.v = *(const u32x4*)(bp + 8);
      #pragma unroll
      for (int i = 0; i < 8; i++) Bs[(bnseg * 16 + i) * 40 + bk] = t0.s[i];
      #pragma unroll
      for (int i = 0; i < 8; i++) Bs[(bnseg * 16 + 8 + i) * 40 + bk] = t1.s[i];
    }
    __syncthreads();
    bfrag afr[4], bfr[4];
    #pragma unroll
    for (int mi = 0; mi < 4; mi++)
      afr[mi] = *(const bfrag*)(As + (wm * 64 + mi * 16 + l16) * 40 + quad * 8);
    #pragma unroll
    for (int ni = 0; ni < 4; ni++)
      bfr[ni] = *(const bfrag*)(Bs + (wn * 64 + ni * 16 + l16) * 40 + quad * 8);
    #pragma unroll
    for (int mi = 0; mi < 4; mi++)
      #pragma unroll
      for (int ni = 0; ni < 4; ni++)
        acc[mi][ni] = __builtin_amdgcn_mfma_f32_16x16x32_bf16(afr[mi], bfr[ni], acc[mi][ni], 0, 0, 0);
    __syncthreads();
  }

  // epilogue — C/D layout: col = lane&15, row = quad*4 + reg  [verified m89/m91]
  if (MODE == 0) {
    #pragma unroll
    for (int mi = 0; mi < 4; mi++) {
      int rbase = m0 + wm * 64 + mi * 16 + quad * 4;
      #pragma unroll
      for (int ni = 0; ni < 4; ni++) {
        int col = n0 + wn * 64 + ni * 16 + l16;
        float bv = bias[col];
        #pragma unroll
        for (int r = 0; r < 4; r++) {
          float v = acc[mi][ni][r] + bv;
          float g = 0.5f * v * (1.f + erff(v * 0.70710678118654752f));  // exact erf GELU
          H[(size_t)(rbase + r) * N + col] = f2bf(g);
        }
      }
    }
  } else {
    #pragma unroll
    for (int mi = 0; mi < 4; mi++) {
      int rbase = m0 + wm * 64 + mi * 16 + quad * 4;
      float wv[4];
      #pragma unroll
      for (int r = 0; r < 4; r++) wv[r] = w_all[(size_t)(rbase + r) * NE + expert];
      #pragma unroll
      for (int ni = 0; ni < 4; ni++) {
        int col = n0 + wn * 64 + ni * 16 + l16;
        float bv = bias[col];
        #pragma unroll
        for (int r = 0; r < 4; r++) {
          size_t oidx = (size_t)(rbase + r) * N + col;
          out[oidx] += wv[r] * (acc[mi][ni][r] + bv);  // safe: expert launches serialize on stream
        }
      }
    }
  }
}

extern "C" void kernel_launch(void* const* d_in, const int* in_sizes, int n_in,
                              void* d_out, int out_size, void* d_ws, size_t ws_size,
                              hipStream_t stream) {
  const float* x  = (const float*)d_in[0];
  const float* rw = (const float*)d_in[1];
  const float* W1 = (const float*)d_in[2];
  const float* b1 = (const float*)d_in[3];
  const float* W2 = (const float*)d_in[4];
  const float* b2 = (const float*)d_in[5];
  float* out = (float*)d_out;  // [NTOK*DM] output, then 1 aux scalar

  char* p = (char*)d_ws;
  auto carve = [&](size_t bytes) { char* r = p; p += (bytes + 255) & ~(size_t)255; return r; };
  short* xb    = (short*)carve((size_t)NTOK * DM * 2);
  short* w1b   = (short*)carve((size_t)NE * DM * DFF * 2);
  short* w2b   = (short*)carve((size_t)NE * DFF * DM * 2);
  short* Hbuf  = (short*)carve((size_t)NTOK * DFF * 2);
  float* w_all = (float*)carve((size_t)NTOK * NE * 4);
  float* stats = (float*)carve(16 * 4);

  hipMemsetAsync(stats, 0, 16 * 4, stream);
  hipMemsetAsync(out, 0, ((size_t)NTOK * DM + 1) * 4, stream);

  cvt_kernel<<<(NTOK * DM / 4 + 255) / 256, 256, 0, stream>>>(x, xb, NTOK * DM / 4);
  cvt_kernel<<<(NE * DM * DFF / 4 + 255) / 256, 256, 0, stream>>>(W1, w1b, NE * DM * DFF / 4);
  cvt_kernel<<<(NE * DFF * DM / 4 + 255) / 256, 256, 0, stream>>>(W2, w2b, NE * DFF * DM / 4);
  router_kernel<<<NTOK / 4, 256, 0, stream>>>(x, rw, w_all, stats);
  aux_kernel<<<1, 1, 0, stream>>>(stats, out + (size_t)NTOK * DM);

  for (int e = 0; e < NE; e++) {
    gemm_kernel<0><<<dim3(64, 16), 256, 0, stream>>>(
        xb, w1b + (size_t)e * DM * DFF, b1 + (size_t)e * DFF,
        Hbuf, nullptr, nullptr, e, NTOK, DFF, DM);
    gemm_kernel<1><<<dim3(64, 4), 256, 0, stream>>>(
        Hbuf, w2b + (size_t)e * DFF * DM, b2 + (size_t)e * DM,
        nullptr, out, w_all, e, NTOK, DM, DFF);
  }
}

// Round 2
// 935.468 us; speedup vs baseline: 1.5037x; 1.5037x over previous
//
#include <hip/hip_runtime.h>
#include <hip/hip_bf16.h>
#include <math.h>

#define NTOK 8192
#define DM 512
#define DFF 2048
#define NE 8

typedef __attribute__((ext_vector_type(8))) short bfrag;     // 8 bf16 (4 VGPRs)
typedef __attribute__((ext_vector_type(4))) float f32x4;
typedef __attribute__((ext_vector_type(4))) unsigned int u32x4;
typedef __attribute__((ext_vector_type(4))) short s16x4;

// async global->LDS, 16B per lane; LDS dest = wave-uniform base + lane*16
#define GLD_LDS16(gp, lp) __builtin_amdgcn_global_load_lds( \
    (const __attribute__((address_space(1))) void*)(gp),    \
    (__attribute__((address_space(3))) void*)(lp), 16, 0, 0)

__device__ __forceinline__ short f2bf(float f) {
  unsigned u = __builtin_bit_cast(unsigned, f);
  u += 0x7fffu + ((u >> 16) & 1u);   // round-to-nearest-even
  return (short)(u >> 16);
}

// ---------------- fp32 -> bf16 conversion (vectorized x4) ----------------
__global__ __launch_bounds__(256) void cvt_kernel(const float* __restrict__ in,
                                                  short* __restrict__ o, int n4) {
  int i = blockIdx.x * 256 + threadIdx.x;
  if (i >= n4) return;
  f32x4 v = ((const f32x4*)in)[i];
  s16x4 s;
  #pragma unroll
  for (int j = 0; j < 4; j++) s[j] = f2bf(v[j]);
  ((s16x4*)o)[i] = s;
}

// ---------------- fp32 -> bf16 transpose-convert ----------------
// in: [NE][R][C] fp32 row-major; out: [NE][C][R] bf16 row-major
__global__ __launch_bounds__(256) void cvtT_kernel(const float* __restrict__ in,
                                                   short* __restrict__ o, int R, int C) {
  __shared__ float t[32][33];
  size_t eoff = (size_t)blockIdx.z * R * C;
  in += eoff; o += eoff;
  int r0 = blockIdx.x * 32, c0 = blockIdx.y * 32;
  int tx = threadIdx.x & 31, ty = threadIdx.x >> 5;   // 32x8 threads
  #pragma unroll
  for (int i = 0; i < 32; i += 8)
    t[ty + i][tx] = in[(size_t)(r0 + ty + i) * C + c0 + tx];
  __syncthreads();
  #pragma unroll
  for (int i = 0; i < 32; i += 8)
    o[(size_t)(c0 + ty + i) * R + r0 + tx] = f2bf(t[tx][ty + i]);
}

// ---------------- router: logits, softmax, top-p routing, aux stats ----------------
__global__ __launch_bounds__(256) void router_kernel(const float* __restrict__ x,
                                                     const float* __restrict__ rw,
                                                     float* __restrict__ w_all,
                                                     float* __restrict__ stats) {
  __shared__ float s_cnt[NE], s_ps[NE];
  if (threadIdx.x < NE) { s_cnt[threadIdx.x] = 0.f; s_ps[threadIdx.x] = 0.f; }
  __syncthreads();
  int wave = threadIdx.x >> 6, lane = threadIdx.x & 63;
  int token = blockIdx.x * 4 + wave;
  const float* xt = x + (size_t)token * DM;
  float acc[NE];
  #pragma unroll
  for (int e = 0; e < NE; e++) acc[e] = 0.f;
  #pragma unroll
  for (int kk = 0; kk < DM / 64; kk++) {
    int k = kk * 64 + lane;
    float xv = xt[k];
    f32x4 r0 = *(const f32x4*)(rw + k * NE);
    f32x4 r1 = *(const f32x4*)(rw + k * NE + 4);
    acc[0] += xv * r0[0]; acc[1] += xv * r0[1]; acc[2] += xv * r0[2]; acc[3] += xv * r0[3];
    acc[4] += xv * r1[0]; acc[5] += xv * r1[1]; acc[6] += xv * r1[2]; acc[7] += xv * r1[3];
  }
  #pragma unroll
  for (int off = 32; off >= 1; off >>= 1) {
    #pragma unroll
    for (int e = 0; e < NE; e++) acc[e] += __shfl_xor(acc[e], off, 64);
  }
  float mx = acc[0];
  #pragma unroll
  for (int e = 1; e < NE; e++) mx = fmaxf(mx, acc[e]);
  float p[NE]; float sum = 0.f;
  #pragma unroll
  for (int e = 0; e < NE; e++) { p[e] = expf(acc[e] - mx); sum += p[e]; }
  float inv = 1.f / sum;
  #pragma unroll
  for (int e = 0; e < NE; e++) p[e] *= inv;
  float sp[4]; int si[4]; unsigned used = 0;
  #pragma unroll
  for (int s = 0; s < 4; s++) {
    float bp = -1.f; int bi = 0;
    #pragma unroll
    for (int e = 0; e < NE; e++)
      if (!((used >> e) & 1u) && p[e] > bp) { bp = p[e]; bi = e; }
    used |= 1u << bi; sp[s] = bp; si[s] = bi;
  }
  float csum = 0.f, wsum = 0.f; bool keep[4];
  #pragma unroll
  for (int s = 0; s < 4; s++) {
    keep[s] = (s < 1) || (csum < 0.9f);
    csum += sp[s];
    if (keep[s]) wsum += sp[s];
  }
  wsum = fmaxf(wsum, 1e-9f);
  float we[NE];
  #pragma unroll
  for (int e = 0; e < NE; e++) we[e] = 0.f;
  #pragma unroll
  for (int s = 0; s < 4; s++) if (keep[s]) we[si[s]] = sp[s] / wsum;

  if (lane == 0) {
    #pragma unroll
    for (int e = 0; e < NE; e++) w_all[(size_t)token * NE + e] = we[e];
    #pragma unroll
    for (int e = 0; e < NE; e++) atomicAdd(&s_ps[e], p[e]);
    #pragma unroll
    for (int s = 0; s < 4; s++) if (keep[s]) atomicAdd(&s_cnt[si[s]], 1.f);
  }
  __syncthreads();
  if (threadIdx.x < NE) {
    atomicAdd(&stats[threadIdx.x], s_cnt[threadIdx.x]);
    atomicAdd(&stats[NE + threadIdx.x], s_ps[threadIdx.x]);
  }
}

__global__ void aux_kernel(const float* __restrict__ stats, float* __restrict__ auxp) {
  float tot = 0.f;
  for (int e = 0; e < NE; e++) tot += stats[e];
  float t = fmaxf(tot, 1.f);
  float s = 0.f;
  for (int e = 0; e < NE; e++) s += (stats[e] / t) * (stats[NE + e] / (float)NTOK);
  auxp[0] = 0.01f * (float)NE * s;
}

// ---------------- bf16 MFMA GEMM (m97 structure) ----------------
// A: M x K bf16 row-major.  Bt: N x K bf16 row-major (pre-transposed).
// Both staged to LDS [row][32] (64B rows, no pad) via global_load_lds x16B.
// MODE 0: H = bf16(gelu_exact(A@Bt^T + bias))
// MODE 1: out += w_all[row][expert] * (A@Bt^T + bias)
template <int MODE, int BM, int BN>
__global__ __launch_bounds__(256) void gemm_kernel(
    const short* __restrict__ A, const short* __restrict__ Bt,
    const float* __restrict__ bias,
    short* __restrict__ H, float* __restrict__ out, const float* __restrict__ w_all,
    int expert, int M, int N, int K) {
  constexpr int FM = BM / 32;   // frags per wave (waves 2x2, per-wave BM/2 x BN/2)
  constexpr int FN = BN / 32;
  __shared__ __align__(16) short As[BM * 32];
  __shared__ __align__(16) short Bs[BN * 32];
  int tid = threadIdx.x;
  int wave = tid >> 6, lane = tid & 63;
  int wm = wave >> 1, wn = wave & 1;
  int quad = lane >> 4, l16 = lane & 15;
  int m0 = blockIdx.x * BM, n0 = blockIdx.y * BN;

  f32x4 acc[FM][FN];
  #pragma unroll
  for (int i = 0; i < FM; i++)
    #pragma unroll
    for (int j = 0; j < FN; j++) acc[i][j] = (f32x4){0.f, 0.f, 0.f, 0.f};

  const short* Abase = A + (size_t)m0 * K;
  const short* Bbase = Bt + (size_t)n0 * K;

  for (int kt = 0; kt < K; kt += 32) {
    // stage A: BM x 32 (16B/lane chunks; wave-uniform LDS base + lane*16)
    #pragma unroll
    for (int h = 0; h < BM / 64; h++) {
      int c = ((h << 2) + wave) * 64 + lane;           // chunk id
      GLD_LDS16(Abase + (size_t)(c >> 2) * K + kt + ((c & 3) << 3),
                As + ((h << 2) + wave) * 512);
    }
    // stage B: BN x 32
    #pragma unroll
    for (int h = 0; h < BN / 64; h++) {
      int c = ((h << 2) + wave) * 64 + lane;
      GLD_LDS16(Bbase + (size_t)(c >> 2) * K + kt + ((c & 3) << 3),
                Bs + ((h << 2) + wave) * 512);
    }
    __syncthreads();   // drains vmcnt(0): LDS tiles ready
    bfrag afr[FM], bfr[FN];
    #pragma unroll
    for (int mi = 0; mi < FM; mi++)
      afr[mi] = *(const bfrag*)(As + (wm * (BM / 2) + mi * 16 + l16) * 32 + quad * 8);
    #pragma unroll
    for (int ni = 0; ni < FN; ni++)
      bfr[ni] = *(const bfrag*)(Bs + (wn * (BN / 2) + ni * 16 + l16) * 32 + quad * 8);
    #pragma unroll
    for (int mi = 0; mi < FM; mi++)
      #pragma unroll
      for (int ni = 0; ni < FN; ni++)
        acc[mi][ni] = __builtin_amdgcn_mfma_f32_16x16x32_bf16(afr[mi], bfr[ni], acc[mi][ni], 0, 0, 0);
    __syncthreads();   // compute done before restage
  }

  // epilogue — C/D layout: col = lane&15, row = quad*4 + reg  [m89/m91]
  if (MODE == 0) {
    #pragma unroll
    for (int mi = 0; mi < FM; mi++) {
      int rbase = m0 + wm * (BM / 2) + mi * 16 + quad * 4;
      #pragma unroll
      for (int ni = 0; ni < FN; ni++) {
        int col = n0 + wn * (BN / 2) + ni * 16 + l16;
        float bv = bias[col];
        #pragma unroll
        for (int r = 0; r < 4; r++) {
          float v = acc[mi][ni][r] + bv;
          float g = 0.5f * v * (1.f + erff(v * 0.70710678118654752f));  // exact erf GELU
          H[(size_t)(rbase + r) * N + col] = f2bf(g);
        }
      }
    }
  } else {
    #pragma unroll
    for (int mi = 0; mi < FM; mi++) {
      int rbase = m0 + wm * (BM / 2) + mi * 16 + quad * 4;
      float wv[4];
      #pragma unroll
      for (int r = 0; r < 4; r++) wv[r] = w_all[(size_t)(rbase + r) * NE + expert];
      #pragma unroll
      for (int ni = 0; ni < FN; ni++) {
        int col = n0 + wn * (BN / 2) + ni * 16 + l16;
        float bv = bias[col];
        #pragma unroll
        for (int r = 0; r < 4; r++) {
          size_t oidx = (size_t)(rbase + r) * N + col;
          out[oidx] += wv[r] * (acc[mi][ni][r] + bv);  // safe: expert launches serialize on stream
        }
      }
    }
  }
}

extern "C" void kernel_launch(void* const* d_in, const int* in_sizes, int n_in,
                              void* d_out, int out_size, void* d_ws, size_t ws_size,
                              hipStream_t stream) {
  const float* x  = (const float*)d_in[0];
  const float* rw = (const float*)d_in[1];
  const float* W1 = (const float*)d_in[2];
  const float* b1 = (const float*)d_in[3];
  const float* W2 = (const float*)d_in[4];
  const float* b2 = (const float*)d_in[5];
  float* out = (float*)d_out;  // [NTOK*DM] output, then 1 aux scalar

  char* p = (char*)d_ws;
  auto carve = [&](size_t bytes) { char* r = p; p += (bytes + 255) & ~(size_t)255; return r; };
  short* xb    = (short*)carve((size_t)NTOK * DM * 2);
  short* w1b   = (short*)carve((size_t)NE * DM * DFF * 2);   // [e][DFF][DM] (transposed)
  short* w2b   = (short*)carve((size_t)NE * DFF * DM * 2);   // [e][DM][DFF] (transposed)
  short* Hbuf  = (short*)carve((size_t)NTOK * DFF * 2);
  float* w_all = (float*)carve((size_t)NTOK * NE * 4);
  float* stats = (float*)carve(16 * 4);

  hipMemsetAsync(stats, 0, 16 * 4, stream);
  hipMemsetAsync(out, 0, ((size_t)NTOK * DM + 1) * 4, stream);

  cvt_kernel<<<(NTOK * DM / 4 + 255) / 256, 256, 0, stream>>>(x, xb, NTOK * DM / 4);
  // W1 [e][DM][DFF] -> w1b [e][DFF][DM]
  cvtT_kernel<<<dim3(DM / 32, DFF / 32, NE), 256, 0, stream>>>(W1, w1b, DM, DFF);
  // W2 [e][DFF][DM] -> w2b [e][DM][DFF]
  cvtT_kernel<<<dim3(DFF / 32, DM / 32, NE), 256, 0, stream>>>(W2, w2b, DFF, DM);
  router_kernel<<<NTOK / 4, 256, 0, stream>>>(x, rw, w_all, stats);
  aux_kernel<<<1, 1, 0, stream>>>(stats, out + (size_t)NTOK * DM);

  for (int e = 0; e < NE; e++) {
    gemm_kernel<0, 128, 128><<<dim3(NTOK / 128, DFF / 128), 256, 0, stream>>>(
        xb, w1b + (size_t)e * DM * DFF, b1 + (size_t)e * DFF,
        Hbuf, nullptr, nullptr, e, NTOK, DFF, DM);
    gemm_kernel<1, 128, 64><<<dim3(NTOK / 128, DM / 64), 256, 0, stream>>>(
        Hbuf, w2b + (size_t)e * DFF * DM, b2 + (size_t)e * DM,
        nullptr, out, w_all, e, NTOK, DM, DFF);
  }
}

// Round 3
// 501.034 us; speedup vs baseline: 2.8076x; 1.8671x over previous
//
#include <hip/hip_runtime.h>
#include <hip/hip_bf16.h>
#include <math.h>

#define NTOK 8192
#define DM 512
#define DFF 2048
#define NE 8
#define ROWCAP 33792   // 32768 assignments max + 8*128 padding

typedef __attribute__((ext_vector_type(8))) short bfrag;
typedef __attribute__((ext_vector_type(4))) float f32x4;
typedef __attribute__((ext_vector_type(4))) unsigned int u32x4;
typedef __attribute__((ext_vector_type(4))) short s16x4;

// async global->LDS, 16B/lane; LDS dest = wave-uniform base + lane*16 (global addr may be per-lane)
#define GLD_LDS16(gp, lp) __builtin_amdgcn_global_load_lds( \
    (const __attribute__((address_space(1))) void*)(gp),    \
    (__attribute__((address_space(3))) void*)(lp), 16, 0, 0)

__device__ __forceinline__ short f2bf(float f) {
  unsigned u = __builtin_bit_cast(unsigned, f);
  u += 0x7fffu + ((u >> 16) & 1u);
  return (short)(u >> 16);
}
__device__ __forceinline__ float bf2f(short s) {
  unsigned u = ((unsigned)(unsigned short)s) << 16;
  return __builtin_bit_cast(float, u);
}

// ---------------- fp32 -> bf16 conversion ----------------
__global__ __launch_bounds__(256) void cvt_kernel(const float* __restrict__ in,
                                                  short* __restrict__ o, int n4) {
  int i = blockIdx.x * 256 + threadIdx.x;
  if (i >= n4) return;
  f32x4 v = ((const f32x4*)in)[i];
  s16x4 s;
  #pragma unroll
  for (int j = 0; j < 4; j++) s[j] = f2bf(v[j]);
  ((s16x4*)o)[i] = s;
}

// ---------------- fp32 -> bf16 transpose-convert ----------------
__global__ __launch_bounds__(256) void cvtT_kernel(const float* __restrict__ in,
                                                   short* __restrict__ o, int R, int C) {
  __shared__ float t[32][33];
  size_t eoff = (size_t)blockIdx.z * R * C;
  in += eoff; o += eoff;
  int r0 = blockIdx.x * 32, c0 = blockIdx.y * 32;
  int tx = threadIdx.x & 31, ty = threadIdx.x >> 5;
  #pragma unroll
  for (int i = 0; i < 32; i += 8)
    t[ty + i][tx] = in[(size_t)(r0 + ty + i) * C + c0 + tx];
  __syncthreads();
  #pragma unroll
  for (int i = 0; i < 32; i += 8)
    o[(size_t)(c0 + ty + i) * R + r0 + tx] = f2bf(t[tx][ty + i]);
}

// ---------------- router: 8 tokens/wave, partial stats per block (no global atomics) ----------------
__global__ __launch_bounds__(256) void router_kernel(const float* __restrict__ x,
                                                     const float* __restrict__ rw,
                                                     float* __restrict__ w_all,
                                                     int* __restrict__ sel_e,
                                                     float* __restrict__ sel_w,
                                                     float* __restrict__ part) {
  __shared__ float s_cnt[NE], s_ps[NE];
  int tid = threadIdx.x;
  if (tid < NE) { s_cnt[tid] = 0.f; s_ps[tid] = 0.f; }
  __syncthreads();
  int wave = tid >> 6, lane = tid & 63;
  float myc[NE], myp[NE];
  #pragma unroll
  for (int e = 0; e < NE; e++) { myc[e] = 0.f; myp[e] = 0.f; }

  for (int i = 0; i < 8; i++) {
    int token = blockIdx.x * 32 + wave * 8 + i;
    const float* xt = x + (size_t)token * DM;
    float acc[NE];
    #pragma unroll
    for (int e = 0; e < NE; e++) acc[e] = 0.f;
    #pragma unroll
    for (int kk = 0; kk < DM / 64; kk++) {
      int k = kk * 64 + lane;
      float xv = xt[k];
      f32x4 r0 = *(const f32x4*)(rw + k * NE);
      f32x4 r1 = *(const f32x4*)(rw + k * NE + 4);
      acc[0] += xv * r0[0]; acc[1] += xv * r0[1]; acc[2] += xv * r0[2]; acc[3] += xv * r0[3];
      acc[4] += xv * r1[0]; acc[5] += xv * r1[1]; acc[6] += xv * r1[2]; acc[7] += xv * r1[3];
    }
    #pragma unroll
    for (int off = 32; off >= 1; off >>= 1) {
      #pragma unroll
      for (int e = 0; e < NE; e++) acc[e] += __shfl_xor(acc[e], off, 64);
    }
    float mx = acc[0];
    #pragma unroll
    for (int e = 1; e < NE; e++) mx = fmaxf(mx, acc[e]);
    float p[NE]; float sum = 0.f;
    #pragma unroll
    for (int e = 0; e < NE; e++) { p[e] = expf(acc[e] - mx); sum += p[e]; }
    float inv = 1.f / sum;
    #pragma unroll
    for (int e = 0; e < NE; e++) p[e] *= inv;
    // stable top-4 (ties -> lowest index)
    float sp[4]; int si[4]; unsigned used = 0;
    #pragma unroll
    for (int s = 0; s < 4; s++) {
      float bp = -1.f; int bi = 0;
      #pragma unroll
      for (int e = 0; e < NE; e++)
        if (!((used >> e) & 1u) && p[e] > bp) { bp = p[e]; bi = e; }
      used |= 1u << bi; sp[s] = bp; si[s] = bi;
    }
    float csum = 0.f, wsum = 0.f; bool keep[4];
    #pragma unroll
    for (int s = 0; s < 4; s++) {
      keep[s] = (s < 1) || (csum < 0.9f);
      csum += sp[s];
      if (keep[s]) wsum += sp[s];
    }
    wsum = fmaxf(wsum, 1e-9f);
    if (lane == 0) {
      float we[NE];
      #pragma unroll
      for (int e = 0; e < NE; e++) we[e] = 0.f;
      #pragma unroll
      for (int s = 0; s < 4; s++) if (keep[s]) we[si[s]] = sp[s] / wsum;
      #pragma unroll
      for (int e = 0; e < NE; e++) w_all[(size_t)token * NE + e] = we[e];
      #pragma unroll
      for (int s = 0; s < 4; s++) {
        sel_e[token * 4 + s] = keep[s] ? si[s] : -1;
        sel_w[token * 4 + s] = keep[s] ? sp[s] / wsum : 0.f;
      }
      #pragma unroll
      for (int e = 0; e < NE; e++) myp[e] += p[e];
      #pragma unroll
      for (int s = 0; s < 4; s++) if (keep[s]) myc[si[s]] += 1.f;
    }
  }
  if (lane == 0) {
    #pragma unroll
    for (int e = 0; e < NE; e++) { atomicAdd(&s_cnt[e], myc[e]); atomicAdd(&s_ps[e], myp[e]); }
  }
  __syncthreads();
  if (tid < NE) {
    part[blockIdx.x * 16 + tid] = s_cnt[tid];
    part[blockIdx.x * 16 + 8 + tid] = s_ps[tid];
  }
}

// ---------------- prep: reduce partial stats -> aux scalar + expert bases ----------------
// meta layout: [0..8) counts, [8..16) bases (128-aligned prefix), [16..24) running slot counters
__global__ void prep_kernel(const float* __restrict__ part, float* __restrict__ auxp,
                            int* __restrict__ meta) {
  __shared__ float red[16];
  int tid = threadIdx.x;
  if (tid < 16) {
    float s = 0.f;
    for (int b = 0; b < 256; b++) s += part[b * 16 + tid];
    red[tid] = s;
  }
  __syncthreads();
  if (tid == 0) {
    float tot = 0.f;
    for (int e = 0; e < NE; e++) tot += red[e];
    float t = fmaxf(tot, 1.f), s = 0.f;
    for (int e = 0; e < NE; e++) s += (red[e] / t) * (red[NE + e] / (float)NTOK);
    auxp[0] = 0.01f * (float)NE * s;
    int off = 0;
    for (int e = 0; e < NE; e++) {
      int c = (int)(red[e] + 0.5f);
      meta[e] = c; meta[8 + e] = off;
      off += (c + 127) & ~127;
    }
  }
  if (tid < NE) meta[16 + tid] = 0;
}

// ---------------- build compact assignment lists ----------------
__global__ __launch_bounds__(256) void build_kernel(const int* __restrict__ sel_e,
                                                    const float* __restrict__ sel_w,
                                                    int* __restrict__ meta,
                                                    int* __restrict__ mlist,
                                                    float* __restrict__ wrow,
                                                    int* __restrict__ arow) {
  __shared__ int lcnt[NE], roff[NE];
  int tid = threadIdx.x;
  if (tid < NE) lcnt[tid] = 0;
  __syncthreads();
  int t = blockIdx.x * 32 + tid;
  int slots[4], es[4];
  bool active = tid < 32;
  if (active) {
    #pragma unroll
    for (int s = 0; s < 4; s++) {
      es[s] = sel_e[t * 4 + s];
      slots[s] = (es[s] >= 0) ? atomicAdd(&lcnt[es[s]], 1) : -1;
    }
  }
  __syncthreads();
  if (tid < NE) roff[tid] = atomicAdd(&meta[16 + tid], lcnt[tid]);
  __syncthreads();
  if (active) {
    #pragma unroll
    for (int s = 0; s < 4; s++) {
      int e = es[s];
      if (e >= 0) {
        int hrow = meta[8 + e] + roff[e] + slots[s];
        mlist[hrow] = t;
        wrow[hrow] = sel_w[t * 4 + s];
        arow[t * 4 + s] = hrow;
      } else {
        arow[t * 4 + s] = -1;
      }
    }
  }
}

// ---------------- sparse GEMM1: H[hrow] = bf16(gelu(x[tok] @ W1^T + b1)) ----------------
__global__ __launch_bounds__(256) void gemm1_sp(const short* __restrict__ A,
                                                const short* __restrict__ W1t,
                                                const float* __restrict__ b1,
                                                short* __restrict__ H,
                                                const int* __restrict__ mlist,
                                                const int* __restrict__ meta) {
  __shared__ __align__(16) short As[128 * 32];
  __shared__ __align__(16) short Bs[128 * 32];
  int e = blockIdx.x >> 6, j = blockIdx.x & 63;
  int cnt = meta[e];
  if (j * 128 >= cnt) return;
  int base = meta[8 + e];
  int tid = threadIdx.x, wave = tid >> 6, lane = tid & 63;
  int wm = wave >> 1, wn = wave & 1, quad = lane >> 4, l16 = lane & 15;
  int n0 = blockIdx.y * 128;
  const short* Bt = W1t + (size_t)e * DFF * DM;
  int seg = lane & 3, rr = wave * 16 + (lane >> 2);
  int rl0 = j * 128 + rr, rl1 = rl0 + 64;
  int t0 = mlist[base + (rl0 < cnt ? rl0 : cnt - 1)];
  int t1 = mlist[base + (rl1 < cnt ? rl1 : cnt - 1)];
  const short* a0 = A + (size_t)t0 * DM + seg * 8;
  const short* a1 = A + (size_t)t1 * DM + seg * 8;
  const short* bp0 = Bt + (size_t)(n0 + rr) * DM + seg * 8;
  const short* bp1 = bp0 + (size_t)64 * DM;

  f32x4 acc[4][4];
  #pragma unroll
  for (int i = 0; i < 4; i++)
    #pragma unroll
    for (int jj = 0; jj < 4; jj++) acc[i][jj] = (f32x4){0.f, 0.f, 0.f, 0.f};

  for (int kt = 0; kt < DM; kt += 32) {
    GLD_LDS16(a0 + kt, As + wave * 512);
    GLD_LDS16(a1 + kt, As + (4 + wave) * 512);
    GLD_LDS16(bp0 + kt, Bs + wave * 512);
    GLD_LDS16(bp1 + kt, Bs + (4 + wave) * 512);
    __syncthreads();
    bfrag afr[4], bfr[4];
    #pragma unroll
    for (int mi = 0; mi < 4; mi++)
      afr[mi] = *(const bfrag*)(As + (wm * 64 + mi * 16 + l16) * 32 + quad * 8);
    #pragma unroll
    for (int ni = 0; ni < 4; ni++)
      bfr[ni] = *(const bfrag*)(Bs + (wn * 64 + ni * 16 + l16) * 32 + quad * 8);
    #pragma unroll
    for (int mi = 0; mi < 4; mi++)
      #pragma unroll
      for (int ni = 0; ni < 4; ni++)
        acc[mi][ni] = __builtin_amdgcn_mfma_f32_16x16x32_bf16(afr[mi], bfr[ni], acc[mi][ni], 0, 0, 0);
    __syncthreads();
  }
  const float* bb = b1 + (size_t)e * DFF;
  #pragma unroll
  for (int mi = 0; mi < 4; mi++) {
    int rbase = base + j * 128 + wm * 64 + mi * 16 + quad * 4;
    #pragma unroll
    for (int ni = 0; ni < 4; ni++) {
      int col = n0 + wn * 64 + ni * 16 + l16;
      float bv = bb[col];
      #pragma unroll
      for (int r = 0; r < 4; r++) {
        float v = acc[mi][ni][r] + bv;
        float g = 0.5f * v * (1.f + erff(v * 0.70710678118654752f));
        H[(size_t)(rbase + r) * DFF + col] = f2bf(g);
      }
    }
  }
}

// ---------------- sparse GEMM2: partial[hrow] = bf16(wrow[hrow] * (H[hrow] @ W2^T + b2)) ----------------
__global__ __launch_bounds__(256) void gemm2_sp(const short* __restrict__ H,
                                                const short* __restrict__ W2t,
                                                const float* __restrict__ b2,
                                                short* __restrict__ partial,
                                                const float* __restrict__ wrow,
                                                const int* __restrict__ meta) {
  __shared__ __align__(16) short As[128 * 32];
  __shared__ __align__(16) short Bs[128 * 32];
  int e = blockIdx.x >> 6, j = blockIdx.x & 63;
  int cnt = meta[e];
  if (j * 128 >= cnt) return;
  int base = meta[8 + e];
  int tid = threadIdx.x, wave = tid >> 6, lane = tid & 63;
  int wm = wave >> 1, wn = wave & 1, quad = lane >> 4, l16 = lane & 15;
  int n0 = blockIdx.y * 128;
  const short* Bt = W2t + (size_t)e * DM * DFF;
  int seg = lane & 3, rr = wave * 16 + (lane >> 2);
  const short* a0 = H + (size_t)(base + j * 128 + rr) * DFF + seg * 8;
  const short* a1 = a0 + (size_t)64 * DFF;
  const short* bp0 = Bt + (size_t)(n0 + rr) * DFF + seg * 8;
  const short* bp1 = bp0 + (size_t)64 * DFF;

  f32x4 acc[4][4];
  #pragma unroll
  for (int i = 0; i < 4; i++)
    #pragma unroll
    for (int jj = 0; jj < 4; jj++) acc[i][jj] = (f32x4){0.f, 0.f, 0.f, 0.f};

  for (int kt = 0; kt < DFF; kt += 32) {
    GLD_LDS16(a0 + kt, As + wave * 512);
    GLD_LDS16(a1 + kt, As + (4 + wave) * 512);
    GLD_LDS16(bp0 + kt, Bs + wave * 512);
    GLD_LDS16(bp1 + kt, Bs + (4 + wave) * 512);
    __syncthreads();
    bfrag afr[4], bfr[4];
    #pragma unroll
    for (int mi = 0; mi < 4; mi++)
      afr[mi] = *(const bfrag*)(As + (wm * 64 + mi * 16 + l16) * 32 + quad * 8);
    #pragma unroll
    for (int ni = 0; ni < 4; ni++)
      bfr[ni] = *(const bfrag*)(Bs + (wn * 64 + ni * 16 + l16) * 32 + quad * 8);
    #pragma unroll
    for (int mi = 0; mi < 4; mi++)
      #pragma unroll
      for (int ni = 0; ni < 4; ni++)
        acc[mi][ni] = __builtin_amdgcn_mfma_f32_16x16x32_bf16(afr[mi], bfr[ni], acc[mi][ni], 0, 0, 0);
    __syncthreads();
  }
  const float* bb = b2 + (size_t)e * DM;
  #pragma unroll
  for (int mi = 0; mi < 4; mi++) {
    int rbase = base + j * 128 + wm * 64 + mi * 16 + quad * 4;
    #pragma unroll
    for (int ni = 0; ni < 4; ni++) {
      int col = n0 + wn * 64 + ni * 16 + l16;
      float bv = bb[col];
      #pragma unroll
      for (int r = 0; r < 4; r++) {
        float w = wrow[rbase + r];
        partial[(size_t)(rbase + r) * DM + col] = f2bf(w * (acc[mi][ni][r] + bv));
      }
    }
  }
}

// ---------------- combine: out[t] = sum of token's weighted partials ----------------
__global__ __launch_bounds__(256) void combine_kernel(const short* __restrict__ partial,
                                                      const int* __restrict__ arow,
                                                      float* __restrict__ out) {
  int gid = blockIdx.x * 256 + threadIdx.x;
  int t = gid >> 6, c0 = (gid & 63) << 3;
  const int* ar = arow + t * 4;
  float o[8];
  #pragma unroll
  for (int k = 0; k < 8; k++) o[k] = 0.f;
  #pragma unroll
  for (int s = 0; s < 4; s++) {
    int a = ar[s];
    if (a >= 0) {
      union { u32x4 v; short s16[8]; } buf;
      buf.v = *(const u32x4*)(partial + (size_t)a * DM + c0);
      #pragma unroll
      for (int k = 0; k < 8; k++) o[k] += bf2f(buf.s16[k]);
    }
  }
  float* op = out + (size_t)t * DM + c0;
  *(f32x4*)op = (f32x4){o[0], o[1], o[2], o[3]};
  *(f32x4*)(op + 4) = (f32x4){o[4], o[5], o[6], o[7]};
}

// ---------------- dense fallback GEMM (R2 structure) ----------------
template <int MODE, int BM, int BN>
__global__ __launch_bounds__(256) void gemm_dense(
    const short* __restrict__ A, const short* __restrict__ Bt,
    const float* __restrict__ bias,
    short* __restrict__ H, float* __restrict__ out, const float* __restrict__ w_all,
    int expert, int M, int N, int K) {
  constexpr int FM = BM / 32;
  constexpr int FN = BN / 32;
  __shared__ __align__(16) short As[BM * 32];
  __shared__ __align__(16) short Bs[BN * 32];
  int tid = threadIdx.x;
  int wave = tid >> 6, lane = tid & 63;
  int wm = wave >> 1, wn = wave & 1;
  int quad = lane >> 4, l16 = lane & 15;
  int m0 = blockIdx.x * BM, n0 = blockIdx.y * BN;

  f32x4 acc[FM][FN];
  #pragma unroll
  for (int i = 0; i < FM; i++)
    #pragma unroll
    for (int j = 0; j < FN; j++) acc[i][j] = (f32x4){0.f, 0.f, 0.f, 0.f};

  const short* Abase = A + (size_t)m0 * K;
  const short* Bbase = Bt + (size_t)n0 * K;

  for (int kt = 0; kt < K; kt += 32) {
    #pragma unroll
    for (int h = 0; h < BM / 64; h++) {
      int c = ((h << 2) + wave) * 64 + lane;
      GLD_LDS16(Abase + (size_t)(c >> 2) * K + kt + ((c & 3) << 3),
                As + ((h << 2) + wave) * 512);
    }
    #pragma unroll
    for (int h = 0; h < BN / 64; h++) {
      int c = ((h << 2) + wave) * 64 + lane;
      GLD_LDS16(Bbase + (size_t)(c >> 2) * K + kt + ((c & 3) << 3),
                Bs + ((h << 2) + wave) * 512);
    }
    __syncthreads();
    bfrag afr[FM], bfr[FN];
    #pragma unroll
    for (int mi = 0; mi < FM; mi++)
      afr[mi] = *(const bfrag*)(As + (wm * (BM / 2) + mi * 16 + l16) * 32 + quad * 8);
    #pragma unroll
    for (int ni = 0; ni < FN; ni++)
      bfr[ni] = *(const bfrag*)(Bs + (wn * (BN / 2) + ni * 16 + l16) * 32 + quad * 8);
    #pragma unroll
    for (int mi = 0; mi < FM; mi++)
      #pragma unroll
      for (int ni = 0; ni < FN; ni++)
        acc[mi][ni] = __builtin_amdgcn_mfma_f32_16x16x32_bf16(afr[mi], bfr[ni], acc[mi][ni], 0, 0, 0);
    __syncthreads();
  }

  if (MODE == 0) {
    #pragma unroll
    for (int mi = 0; mi < FM; mi++) {
      int rbase = m0 + wm * (BM / 2) + mi * 16 + quad * 4;
      #pragma unroll
      for (int ni = 0; ni < FN; ni++) {
        int col = n0 + wn * (BN / 2) + ni * 16 + l16;
        float bv = bias[col];
        #pragma unroll
        for (int r = 0; r < 4; r++) {
          float v = acc[mi][ni][r] + bv;
          float g = 0.5f * v * (1.f + erff(v * 0.70710678118654752f));
          H[(size_t)(rbase + r) * N + col] = f2bf(g);
        }
      }
    }
  } else {
    #pragma unroll
    for (int mi = 0; mi < FM; mi++) {
      int rbase = m0 + wm * (BM / 2) + mi * 16 + quad * 4;
      float wv[4];
      #pragma unroll
      for (int r = 0; r < 4; r++) wv[r] = w_all[(size_t)(rbase + r) * NE + expert];
      #pragma unroll
      for (int ni = 0; ni < FN; ni++) {
        int col = n0 + wn * (BN / 2) + ni * 16 + l16;
        float bv = bias[col];
        #pragma unroll
        for (int r = 0; r < 4; r++) {
          size_t oidx = (size_t)(rbase + r) * N + col;
          out[oidx] += wv[r] * (acc[mi][ni][r] + bv);
        }
      }
    }
  }
}

extern "C" void kernel_launch(void* const* d_in, const int* in_sizes, int n_in,
                              void* d_out, int out_size, void* d_ws, size_t ws_size,
                              hipStream_t stream) {
  const float* x  = (const float*)d_in[0];
  const float* rw = (const float*)d_in[1];
  const float* W1 = (const float*)d_in[2];
  const float* b1 = (const float*)d_in[3];
  const float* W2 = (const float*)d_in[4];
  const float* b2 = (const float*)d_in[5];
  float* out = (float*)d_out;

  char* base_p = (char*)d_ws; char* p = base_p;
  auto carve = [&](size_t bytes) { char* r = p; p += (bytes + 255) & ~(size_t)255; return r; };
  short* xb    = (short*)carve((size_t)NTOK * DM * 2);
  short* w1b   = (short*)carve((size_t)NE * DM * DFF * 2);  // [e][DFF][DM]
  short* w2b   = (short*)carve((size_t)NE * DFF * DM * 2);  // [e][DM][DFF]
  float* w_all = (float*)carve((size_t)NTOK * NE * 4);
  int*   sel_e = (int*)carve((size_t)NTOK * 4 * 4);
  float* sel_w = (float*)carve((size_t)NTOK * 4 * 4);
  float* part  = (float*)carve(256 * 16 * 4);
  int*   meta  = (int*)carve(64 * 4);
  int*   arow  = (int*)carve((size_t)NTOK * 4 * 4);
  int*   mlist = (int*)carve((size_t)ROWCAP * 4);
  float* wrow  = (float*)carve((size_t)ROWCAP * 4);
  short* Hbig  = (short*)carve((size_t)ROWCAP * DFF * 2);   // dense path uses first NTOK rows
  char*  dense_end = p;  // dense path needs everything up to end of Hbig's first NTOK rows
  short* partial = (short*)carve((size_t)ROWCAP * DM * 2);
  size_t need_sp = (size_t)(p - base_p);
  (void)dense_end;
  bool sp = ws_size >= need_sp;

  // common prologue
  cvt_kernel<<<(NTOK * DM / 4 + 255) / 256, 256, 0, stream>>>(x, xb, NTOK * DM / 4);
  cvtT_kernel<<<dim3(DM / 32, DFF / 32, NE), 256, 0, stream>>>(W1, w1b, DM, DFF);
  cvtT_kernel<<<dim3(DFF / 32, DM / 32, NE), 256, 0, stream>>>(W2, w2b, DFF, DM);
  router_kernel<<<256, 256, 0, stream>>>(x, rw, w_all, sel_e, sel_w, part);
  prep_kernel<<<1, 64, 0, stream>>>(part, out + (size_t)NTOK * DM, meta);

  if (sp) {
    build_kernel<<<256, 256, 0, stream>>>(sel_e, sel_w, meta, mlist, wrow, arow);
    gemm1_sp<<<dim3(512, DFF / 128), 256, 0, stream>>>(xb, w1b, b1, Hbig, mlist, meta);
    gemm2_sp<<<dim3(512, DM / 128), 256, 0, stream>>>(Hbig, w2b, b2, partial, wrow, meta);
    combine_kernel<<<NTOK * DM / 8 / 256, 256, 0, stream>>>(partial, arow, out);
  } else {
    hipMemsetAsync(out, 0, (size_t)NTOK * DM * 4, stream);
    for (int e = 0; e < NE; e++) {
      gemm_dense<0, 128, 128><<<dim3(NTOK / 128, DFF / 128), 256, 0, stream>>>(
          xb, w1b + (size_t)e * DM * DFF, b1 + (size_t)e * DFF,
          Hbig, nullptr, nullptr, e, NTOK, DFF, DM);
      gemm_dense<1, 128, 64><<<dim3(NTOK / 128, DM / 64), 256, 0, stream>>>(
          Hbig, w2b + (size_t)e * DFF * DM, b2 + (size_t)e * DM,
          nullptr, out, w_all, e, NTOK, DM, DFF);
    }
  }
}

// Round 4
// 494.564 us; speedup vs baseline: 2.8443x; 1.0131x over previous
//
#include <hip/hip_runtime.h>
#include <hip/hip_bf16.h>
#include <math.h>

#define NTOK 8192
#define DM 512
#define DFF 2048
#define NE 8
#define ROWCAP 34816   // 32768 assignments max + 8*256 granule padding

typedef __attribute__((ext_vector_type(8))) short bfrag;
typedef __attribute__((ext_vector_type(4))) float f32x4;
typedef __attribute__((ext_vector_type(4))) unsigned int u32x4;
typedef __attribute__((ext_vector_type(4))) short s16x4;

// async global->LDS, 16B/lane; LDS dest = wave-uniform base + lane*16 (global addr may be per-lane)
#define GLD_LDS16(gp, lp) __builtin_amdgcn_global_load_lds( \
    (const __attribute__((address_space(1))) void*)(gp),    \
    (__attribute__((address_space(3))) void*)(lp), 16, 0, 0)

__device__ __forceinline__ short f2bf(float f) {
  unsigned u = __builtin_bit_cast(unsigned, f);
  u += 0x7fffu + ((u >> 16) & 1u);
  return (short)(u >> 16);
}
__device__ __forceinline__ float bf2f(short s) {
  unsigned u = ((unsigned)(unsigned short)s) << 16;
  return __builtin_bit_cast(float, u);
}
// tanh-form GELU via hw exp2+rcp (~7 ops). max |diff vs erf-gelu| ~5e-4.
__device__ __forceinline__ float fast_gelu(float v) {
  float u = fmaf(v * v * v, 0.044715f, v) * 0.7978845608f;
  float ex = __builtin_amdgcn_exp2f(u * -2.8853900818f);
  return v * __builtin_amdgcn_rcpf(1.f + ex);
}

// ---------------- fp32 -> bf16 conversion ----------------
__global__ __launch_bounds__(256) void cvt_kernel(const float* __restrict__ in,
                                                  short* __restrict__ o, int n4) {
  int i = blockIdx.x * 256 + threadIdx.x;
  if (i >= n4) return;
  f32x4 v = ((const f32x4*)in)[i];
  s16x4 s;
  #pragma unroll
  for (int j = 0; j < 4; j++) s[j] = f2bf(v[j]);
  ((s16x4*)o)[i] = s;
}

// ---------------- fp32 -> bf16 transpose-convert ----------------
__global__ __launch_bounds__(256) void cvtT_kernel(const float* __restrict__ in,
                                                   short* __restrict__ o, int R, int C) {
  __shared__ float t[32][33];
  size_t eoff = (size_t)blockIdx.z * R * C;
  in += eoff; o += eoff;
  int r0 = blockIdx.x * 32, c0 = blockIdx.y * 32;
  int tx = threadIdx.x & 31, ty = threadIdx.x >> 5;
  #pragma unroll
  for (int i = 0; i < 32; i += 8)
    t[ty + i][tx] = in[(size_t)(r0 + ty + i) * C + c0 + tx];
  __syncthreads();
  #pragma unroll
  for (int i = 0; i < 32; i += 8)
    o[(size_t)(c0 + ty + i) * R + r0 + tx] = f2bf(t[tx][ty + i]);
}

// ---------------- router ----------------
__global__ __launch_bounds__(256) void router_kernel(const float* __restrict__ x,
                                                     const float* __restrict__ rw,
                                                     float* __restrict__ w_all,
                                                     int* __restrict__ sel_e,
                                                     float* __restrict__ sel_w,
                                                     float* __restrict__ part) {
  __shared__ float s_cnt[NE], s_ps[NE];
  int tid = threadIdx.x;
  if (tid < NE) { s_cnt[tid] = 0.f; s_ps[tid] = 0.f; }
  __syncthreads();
  int wave = tid >> 6, lane = tid & 63;
  float myc[NE], myp[NE];
  #pragma unroll
  for (int e = 0; e < NE; e++) { myc[e] = 0.f; myp[e] = 0.f; }

  for (int i = 0; i < 8; i++) {
    int token = blockIdx.x * 32 + wave * 8 + i;
    const float* xt = x + (size_t)token * DM;
    float acc[NE];
    #pragma unroll
    for (int e = 0; e < NE; e++) acc[e] = 0.f;
    #pragma unroll
    for (int kk = 0; kk < DM / 64; kk++) {
      int k = kk * 64 + lane;
      float xv = xt[k];
      f32x4 r0 = *(const f32x4*)(rw + k * NE);
      f32x4 r1 = *(const f32x4*)(rw + k * NE + 4);
      acc[0] += xv * r0[0]; acc[1] += xv * r0[1]; acc[2] += xv * r0[2]; acc[3] += xv * r0[3];
      acc[4] += xv * r1[0]; acc[5] += xv * r1[1]; acc[6] += xv * r1[2]; acc[7] += xv * r1[3];
    }
    #pragma unroll
    for (int off = 32; off >= 1; off >>= 1) {
      #pragma unroll
      for (int e = 0; e < NE; e++) acc[e] += __shfl_xor(acc[e], off, 64);
    }
    float mx = acc[0];
    #pragma unroll
    for (int e = 1; e < NE; e++) mx = fmaxf(mx, acc[e]);
    float p[NE]; float sum = 0.f;
    #pragma unroll
    for (int e = 0; e < NE; e++) { p[e] = expf(acc[e] - mx); sum += p[e]; }
    float inv = 1.f / sum;
    #pragma unroll
    for (int e = 0; e < NE; e++) p[e] *= inv;
    float sp[4]; int si[4]; unsigned used = 0;
    #pragma unroll
    for (int s = 0; s < 4; s++) {
      float bp = -1.f; int bi = 0;
      #pragma unroll
      for (int e = 0; e < NE; e++)
        if (!((used >> e) & 1u) && p[e] > bp) { bp = p[e]; bi = e; }
      used |= 1u << bi; sp[s] = bp; si[s] = bi;
    }
    float csum = 0.f, wsum = 0.f; bool keep[4];
    #pragma unroll
    for (int s = 0; s < 4; s++) {
      keep[s] = (s < 1) || (csum < 0.9f);
      csum += sp[s];
      if (keep[s]) wsum += sp[s];
    }
    wsum = fmaxf(wsum, 1e-9f);
    if (lane == 0) {
      float we[NE];
      #pragma unroll
      for (int e = 0; e < NE; e++) we[e] = 0.f;
      #pragma unroll
      for (int s = 0; s < 4; s++) if (keep[s]) we[si[s]] = sp[s] / wsum;
      #pragma unroll
      for (int e = 0; e < NE; e++) w_all[(size_t)token * NE + e] = we[e];
      #pragma unroll
      for (int s = 0; s < 4; s++) {
        sel_e[token * 4 + s] = keep[s] ? si[s] : -1;
        sel_w[token * 4 + s] = keep[s] ? sp[s] / wsum : 0.f;
      }
      #pragma unroll
      for (int e = 0; e < NE; e++) myp[e] += p[e];
      #pragma unroll
      for (int s = 0; s < 4; s++) if (keep[s]) myc[si[s]] += 1.f;
    }
  }
  if (lane == 0) {
    #pragma unroll
    for (int e = 0; e < NE; e++) { atomicAdd(&s_cnt[e], myc[e]); atomicAdd(&s_ps[e], myp[e]); }
  }
  __syncthreads();
  if (tid < NE) {
    part[blockIdx.x * 16 + tid] = s_cnt[tid];
    part[blockIdx.x * 16 + 8 + tid] = s_ps[tid];
  }
}

// ---------------- prep: aux scalar + expert bases (256-aligned) ----------------
__global__ void prep_kernel(const float* __restrict__ part, float* __restrict__ auxp,
                            int* __restrict__ meta) {
  __shared__ float red[16];
  int tid = threadIdx.x;
  if (tid < 16) {
    float s = 0.f;
    for (int b = 0; b < 256; b++) s += part[b * 16 + tid];
    red[tid] = s;
  }
  __syncthreads();
  if (tid == 0) {
    float tot = 0.f;
    for (int e = 0; e < NE; e++) tot += red[e];
    float t = fmaxf(tot, 1.f), s = 0.f;
    for (int e = 0; e < NE; e++) s += (red[e] / t) * (red[NE + e] / (float)NTOK);
    auxp[0] = 0.01f * (float)NE * s;
    int off = 0;
    for (int e = 0; e < NE; e++) {
      int c = (int)(red[e] + 0.5f);
      meta[e] = c; meta[8 + e] = off;
      off += (c + 255) & ~255;   // 256-granule padding (M-tile = 256)
    }
  }
  if (tid < NE) meta[16 + tid] = 0;
}

// ---------------- build compact assignment lists ----------------
__global__ __launch_bounds__(256) void build_kernel(const int* __restrict__ sel_e,
                                                    const float* __restrict__ sel_w,
                                                    int* __restrict__ meta,
                                                    int* __restrict__ mlist,
                                                    float* __restrict__ wrow,
                                                    int* __restrict__ arow) {
  __shared__ int lcnt[NE], roff[NE];
  int tid = threadIdx.x;
  if (tid < NE) lcnt[tid] = 0;
  __syncthreads();
  int t = blockIdx.x * 32 + tid;
  int slots[4], es[4];
  bool active = tid < 32;
  if (active) {
    #pragma unroll
    for (int s = 0; s < 4; s++) {
      es[s] = sel_e[t * 4 + s];
      slots[s] = (es[s] >= 0) ? atomicAdd(&lcnt[es[s]], 1) : -1;
    }
  }
  __syncthreads();
  if (tid < NE) roff[tid] = atomicAdd(&meta[16 + tid], lcnt[tid]);
  __syncthreads();
  if (active) {
    #pragma unroll
    for (int s = 0; s < 4; s++) {
      int e = es[s];
      if (e >= 0) {
        int hrow = meta[8 + e] + roff[e] + slots[s];
        mlist[hrow] = t;
        wrow[hrow] = sel_w[t * 4 + s];
        arow[t * 4 + s] = hrow;
      } else {
        arow[t * 4 + s] = -1;
      }
    }
  }
}

// ---------------- sparse GEMM1: H[hrow] = bf16(gelu(x[tok] @ W1^T + b1)) ----------------
// block tile 256x128 (MxN), BK=32, waves 2x2, per-wave FM=8 x FN=4.
// Staging: chunk c in [0,1024) for A (256 rows x 4 segs), [0,512) for B.
// c = (g*4 + wave)*64 + lane  ->  row = c>>2, seg = c&3; LDS dest base (g*4+wave)*1024B + lane*16.
__global__ __launch_bounds__(256, 2) void gemm1_sp(const short* __restrict__ A,
                                                   const short* __restrict__ W1t,
                                                   const float* __restrict__ b1,
                                                   short* __restrict__ H,
                                                   const int* __restrict__ mlist,
                                                   const int* __restrict__ meta) {
  __shared__ __align__(16) short As[256 * 32];
  __shared__ __align__(16) short Bs[128 * 32];
  int e = blockIdx.x >> 5, j = blockIdx.x & 31;
  int cnt = meta[e];
  if (j * 256 >= cnt) return;
  int base = meta[8 + e];
  int tid = threadIdx.x, wave = tid >> 6, lane = tid & 63;
  int wm = wave >> 1, wn = wave & 1, quad = lane >> 4, l16 = lane & 15;
  int n0 = blockIdx.y * 128;
  const short* Bt = W1t + (size_t)e * DFF * DM;

  // per-thread staging coords: 4 A-chunks (g=0..3) and 2 B-chunks (g=0..1)
  const short* ag[4]; const short* bg[2];
  #pragma unroll
  for (int g = 0; g < 4; g++) {
    int c = (g * 4 + wave) * 64 + lane;
    int row = c >> 2, seg = c & 3;
    int rl = j * 256 + row;
    int tok = mlist[base + (rl < cnt ? rl : cnt - 1)];
    ag[g] = A + (size_t)tok * DM + seg * 8;
  }
  #pragma unroll
  for (int g = 0; g < 2; g++) {
    int c = (g * 4 + wave) * 64 + lane;
    int row = c >> 2, seg = c & 3;
    bg[g] = Bt + (size_t)(n0 + row) * DM + seg * 8;
  }

  f32x4 acc[8][4];
  #pragma unroll
  for (int i = 0; i < 8; i++)
    #pragma unroll
    for (int jj = 0; jj < 4; jj++) acc[i][jj] = (f32x4){0.f, 0.f, 0.f, 0.f};

  for (int kt = 0; kt < DM; kt += 32) {
    #pragma unroll
    for (int g = 0; g < 4; g++)
      GLD_LDS16(ag[g] + kt, As + (g * 4 + wave) * 512);
    #pragma unroll
    for (int g = 0; g < 2; g++)
      GLD_LDS16(bg[g] + kt, Bs + (g * 4 + wave) * 512);
    __syncthreads();
    bfrag afr[8], bfr[4];
    #pragma unroll
    for (int mi = 0; mi < 8; mi++)
      afr[mi] = *(const bfrag*)(As + (wm * 128 + mi * 16 + l16) * 32 + quad * 8);
    #pragma unroll
    for (int ni = 0; ni < 4; ni++)
      bfr[ni] = *(const bfrag*)(Bs + (wn * 64 + ni * 16 + l16) * 32 + quad * 8);
    #pragma unroll
    for (int mi = 0; mi < 8; mi++)
      #pragma unroll
      for (int ni = 0; ni < 4; ni++)
        acc[mi][ni] = __builtin_amdgcn_mfma_f32_16x16x32_bf16(afr[mi], bfr[ni], acc[mi][ni], 0, 0, 0);
    __syncthreads();
  }
  const float* bb = b1 + (size_t)e * DFF;
  #pragma unroll
  for (int mi = 0; mi < 8; mi++) {
    int rbase = base + j * 256 + wm * 128 + mi * 16 + quad * 4;
    #pragma unroll
    for (int ni = 0; ni < 4; ni++) {
      int col = n0 + wn * 64 + ni * 16 + l16;
      float bv = bb[col];
      #pragma unroll
      for (int r = 0; r < 4; r++)
        H[(size_t)(rbase + r) * DFF + col] = f2bf(fast_gelu(acc[mi][ni][r] + bv));
    }
  }
}

// ---------------- sparse GEMM2: partial[hrow] = bf16(wrow * (H[hrow] @ W2^T + b2)) ----------------
__global__ __launch_bounds__(256, 2) void gemm2_sp(const short* __restrict__ H,
                                                   const short* __restrict__ W2t,
                                                   const float* __restrict__ b2,
                                                   short* __restrict__ partial,
                                                   const float* __restrict__ wrow,
                                                   const int* __restrict__ meta) {
  __shared__ __align__(16) short As[256 * 32];
  __shared__ __align__(16) short Bs[128 * 32];
  int e = blockIdx.x >> 5, j = blockIdx.x & 31;
  int cnt = meta[e];
  if (j * 256 >= cnt) return;
  int base = meta[8 + e];
  int tid = threadIdx.x, wave = tid >> 6, lane = tid & 63;
  int wm = wave >> 1, wn = wave & 1, quad = lane >> 4, l16 = lane & 15;
  int n0 = blockIdx.y * 128;
  const short* Bt = W2t + (size_t)e * DM * DFF;

  const short* ag[4]; const short* bg[2];
  #pragma unroll
  for (int g = 0; g < 4; g++) {
    int c = (g * 4 + wave) * 64 + lane;
    int row = c >> 2, seg = c & 3;
    ag[g] = H + (size_t)(base + j * 256 + row) * DFF + seg * 8;
  }
  #pragma unroll
  for (int g = 0; g < 2; g++) {
    int c = (g * 4 + wave) * 64 + lane;
    int row = c >> 2, seg = c & 3;
    bg[g] = Bt + (size_t)(n0 + row) * DFF + seg * 8;
  }

  f32x4 acc[8][4];
  #pragma unroll
  for (int i = 0; i < 8; i++)
    #pragma unroll
    for (int jj = 0; jj < 4; jj++) acc[i][jj] = (f32x4){0.f, 0.f, 0.f, 0.f};

  for (int kt = 0; kt < DFF; kt += 32) {
    #pragma unroll
    for (int g = 0; g < 4; g++)
      GLD_LDS16(ag[g] + kt, As + (g * 4 + wave) * 512);
    #pragma unroll
    for (int g = 0; g < 2; g++)
      GLD_LDS16(bg[g] + kt, Bs + (g * 4 + wave) * 512);
    __syncthreads();
    bfrag afr[8], bfr[4];
    #pragma unroll
    for (int mi = 0; mi < 8; mi++)
      afr[mi] = *(const bfrag*)(As + (wm * 128 + mi * 16 + l16) * 32 + quad * 8);
    #pragma unroll
    for (int ni = 0; ni < 4; ni++)
      bfr[ni] = *(const bfrag*)(Bs + (wn * 64 + ni * 16 + l16) * 32 + quad * 8);
    #pragma unroll
    for (int mi = 0; mi < 8; mi++)
      #pragma unroll
      for (int ni = 0; ni < 4; ni++)
        acc[mi][ni] = __builtin_amdgcn_mfma_f32_16x16x32_bf16(afr[mi], bfr[ni], acc[mi][ni], 0, 0, 0);
    __syncthreads();
  }
  const float* bb = b2 + (size_t)e * DM;
  #pragma unroll
  for (int mi = 0; mi < 8; mi++) {
    int rbase = base + j * 256 + wm * 128 + mi * 16 + quad * 4;
    #pragma unroll
    for (int ni = 0; ni < 4; ni++) {
      int col = n0 + wn * 64 + ni * 16 + l16;
      float bv = bb[col];
      #pragma unroll
      for (int r = 0; r < 4; r++) {
        float w = wrow[rbase + r];
        partial[(size_t)(rbase + r) * DM + col] = f2bf(w * (acc[mi][ni][r] + bv));
      }
    }
  }
}

// ---------------- combine ----------------
__global__ __launch_bounds__(256) void combine_kernel(const short* __restrict__ partial,
                                                      const int* __restrict__ arow,
                                                      float* __restrict__ out) {
  int gid = blockIdx.x * 256 + threadIdx.x;
  int t = gid >> 6, c0 = (gid & 63) << 3;
  const int* ar = arow + t * 4;
  float o[8];
  #pragma unroll
  for (int k = 0; k < 8; k++) o[k] = 0.f;
  #pragma unroll
  for (int s = 0; s < 4; s++) {
    int a = ar[s];
    if (a >= 0) {
      union { u32x4 v; short s16[8]; } buf;
      buf.v = *(const u32x4*)(partial + (size_t)a * DM + c0);
      #pragma unroll
      for (int k = 0; k < 8; k++) o[k] += bf2f(buf.s16[k]);
    }
  }
  float* op = out + (size_t)t * DM + c0;
  *(f32x4*)op = (f32x4){o[0], o[1], o[2], o[3]};
  *(f32x4*)(op + 4) = (f32x4){o[4], o[5], o[6], o[7]};
}

extern "C" void kernel_launch(void* const* d_in, const int* in_sizes, int n_in,
                              void* d_out, int out_size, void* d_ws, size_t ws_size,
                              hipStream_t stream) {
  const float* x  = (const float*)d_in[0];
  const float* rw = (const float*)d_in[1];
  const float* W1 = (const float*)d_in[2];
  const float* b1 = (const float*)d_in[3];
  const float* W2 = (const float*)d_in[4];
  const float* b2 = (const float*)d_in[5];
  float* out = (float*)d_out;

  char* base_p = (char*)d_ws; char* p = base_p;
  auto carve = [&](size_t bytes) { char* r = p; p += (bytes + 255) & ~(size_t)255; return r; };
  short* xb    = (short*)carve((size_t)NTOK * DM * 2);
  short* w1b   = (short*)carve((size_t)NE * DM * DFF * 2);  // [e][DFF][DM]
  short* w2b   = (short*)carve((size_t)NE * DFF * DM * 2);  // [e][DM][DFF]
  float* w_all = (float*)carve((size_t)NTOK * NE * 4);
  int*   sel_e = (int*)carve((size_t)NTOK * 4 * 4);
  float* sel_w = (float*)carve((size_t)NTOK * 4 * 4);
  float* part  = (float*)carve(256 * 16 * 4);
  int*   meta  = (int*)carve(64 * 4);
  int*   arow  = (int*)carve((size_t)NTOK * 4 * 4);
  int*   mlist = (int*)carve((size_t)ROWCAP * 4);
  float* wrow  = (float*)carve((size_t)ROWCAP * 4);
  short* Hbig  = (short*)carve((size_t)ROWCAP * DFF * 2);
  short* partial = (short*)carve((size_t)ROWCAP * DM * 2);

  cvt_kernel<<<(NTOK * DM / 4 + 255) / 256, 256, 0, stream>>>(x, xb, NTOK * DM / 4);
  cvtT_kernel<<<dim3(DM / 32, DFF / 32, NE), 256, 0, stream>>>(W1, w1b, DM, DFF);
  cvtT_kernel<<<dim3(DFF / 32, DM / 32, NE), 256, 0, stream>>>(W2, w2b, DFF, DM);
  router_kernel<<<256, 256, 0, stream>>>(x, rw, w_all, sel_e, sel_w, part);
  prep_kernel<<<1, 64, 0, stream>>>(part, out + (size_t)NTOK * DM, meta);
  build_kernel<<<256, 256, 0, stream>>>(sel_e, sel_w, meta, mlist, wrow, arow);
  gemm1_sp<<<dim3(256, DFF / 128), 256, 0, stream>>>(xb, w1b, b1, Hbig, mlist, meta);
  gemm2_sp<<<dim3(256, DM / 128), 256, 0, stream>>>(Hbig, w2b, b2, partial, wrow, meta);
  combine_kernel<<<NTOK * DM / 8 / 256, 256, 0, stream>>>(partial, arow, out);
}

// Round 5
// 477.516 us; speedup vs baseline: 2.9459x; 1.0357x over previous
//
#include <hip/hip_runtime.h>
#include <hip/hip_bf16.h>
#include <math.h>

#define NTOK 8192
#define DM 512
#define DFF 2048
#define NE 8
#define ROWCAP 33792   // 32768 assignments max + 8*128 granule padding

typedef __attribute__((ext_vector_type(8))) short bfrag;
typedef __attribute__((ext_vector_type(4))) float f32x4;
typedef __attribute__((ext_vector_type(4))) unsigned int u32x4;
typedef __attribute__((ext_vector_type(4))) short s16x4;

// async global->LDS, 16B/lane; LDS dest = wave-uniform base + lane*16 (global addr may be per-lane)
#define GLD_LDS16(gp, lp) __builtin_amdgcn_global_load_lds( \
    (const __attribute__((address_space(1))) void*)(gp),    \
    (__attribute__((address_space(3))) void*)(lp), 16, 0, 0)

__device__ __forceinline__ short f2bf(float f) {
  unsigned u = __builtin_bit_cast(unsigned, f);
  u += 0x7fffu + ((u >> 16) & 1u);
  return (short)(u >> 16);
}
__device__ __forceinline__ float bf2f(short s) {
  unsigned u = ((unsigned)(unsigned short)s) << 16;
  return __builtin_bit_cast(float, u);
}
// tanh-form GELU via hw exp2+rcp (~7 ops). max |diff vs erf-gelu| ~5e-4.
__device__ __forceinline__ float fast_gelu(float v) {
  float u = fmaf(v * v * v, 0.044715f, v) * 0.7978845608f;
  float ex = __builtin_amdgcn_exp2f(u * -2.8853900818f);
  return v * __builtin_amdgcn_rcpf(1.f + ex);
}

// ---------------- fp32 -> bf16 conversion ----------------
__global__ __launch_bounds__(256) void cvt_kernel(const float* __restrict__ in,
                                                  short* __restrict__ o, int n4) {
  int i = blockIdx.x * 256 + threadIdx.x;
  if (i >= n4) return;
  f32x4 v = ((const f32x4*)in)[i];
  s16x4 s;
  #pragma unroll
  for (int j = 0; j < 4; j++) s[j] = f2bf(v[j]);
  ((s16x4*)o)[i] = s;
}

// ---------------- fp32 -> bf16 transpose-convert ----------------
__global__ __launch_bounds__(256) void cvtT_kernel(const float* __restrict__ in,
                                                   short* __restrict__ o, int R, int C) {
  __shared__ float t[32][33];
  size_t eoff = (size_t)blockIdx.z * R * C;
  in += eoff; o += eoff;
  int r0 = blockIdx.x * 32, c0 = blockIdx.y * 32;
  int tx = threadIdx.x & 31, ty = threadIdx.x >> 5;
  #pragma unroll
  for (int i = 0; i < 32; i += 8)
    t[ty + i][tx] = in[(size_t)(r0 + ty + i) * C + c0 + tx];
  __syncthreads();
  #pragma unroll
  for (int i = 0; i < 32; i += 8)
    o[(size_t)(c0 + ty + i) * R + r0 + tx] = f2bf(t[tx][ty + i]);
}

// ---------------- router ----------------
__global__ __launch_bounds__(256) void router_kernel(const float* __restrict__ x,
                                                     const float* __restrict__ rw,
                                                     int* __restrict__ sel_e,
                                                     float* __restrict__ sel_w,
                                                     float* __restrict__ part) {
  __shared__ float s_cnt[NE], s_ps[NE];
  int tid = threadIdx.x;
  if (tid < NE) { s_cnt[tid] = 0.f; s_ps[tid] = 0.f; }
  __syncthreads();
  int wave = tid >> 6, lane = tid & 63;
  float myc[NE], myp[NE];
  #pragma unroll
  for (int e = 0; e < NE; e++) { myc[e] = 0.f; myp[e] = 0.f; }

  for (int i = 0; i < 8; i++) {
    int token = blockIdx.x * 32 + wave * 8 + i;
    const float* xt = x + (size_t)token * DM;
    float acc[NE];
    #pragma unroll
    for (int e = 0; e < NE; e++) acc[e] = 0.f;
    #pragma unroll
    for (int kk = 0; kk < DM / 64; kk++) {
      int k = kk * 64 + lane;
      float xv = xt[k];
      f32x4 r0 = *(const f32x4*)(rw + k * NE);
      f32x4 r1 = *(const f32x4*)(rw + k * NE + 4);
      acc[0] += xv * r0[0]; acc[1] += xv * r0[1]; acc[2] += xv * r0[2]; acc[3] += xv * r0[3];
      acc[4] += xv * r1[0]; acc[5] += xv * r1[1]; acc[6] += xv * r1[2]; acc[7] += xv * r1[3];
    }
    #pragma unroll
    for (int off = 32; off >= 1; off >>= 1) {
      #pragma unroll
      for (int e = 0; e < NE; e++) acc[e] += __shfl_xor(acc[e], off, 64);
    }
    float mx = acc[0];
    #pragma unroll
    for (int e = 1; e < NE; e++) mx = fmaxf(mx, acc[e]);
    float p[NE]; float sum = 0.f;
    #pragma unroll
    for (int e = 0; e < NE; e++) { p[e] = expf(acc[e] - mx); sum += p[e]; }
    float inv = 1.f / sum;
    #pragma unroll
    for (int e = 0; e < NE; e++) p[e] *= inv;
    float sp[4]; int si[4]; unsigned used = 0;
    #pragma unroll
    for (int s = 0; s < 4; s++) {
      float bp = -1.f; int bi = 0;
      #pragma unroll
      for (int e = 0; e < NE; e++)
        if (!((used >> e) & 1u) && p[e] > bp) { bp = p[e]; bi = e; }
      used |= 1u << bi; sp[s] = bp; si[s] = bi;
    }
    float csum = 0.f, wsum = 0.f; bool keep[4];
    #pragma unroll
    for (int s = 0; s < 4; s++) {
      keep[s] = (s < 1) || (csum < 0.9f);
      csum += sp[s];
      if (keep[s]) wsum += sp[s];
    }
    wsum = fmaxf(wsum, 1e-9f);
    if (lane == 0) {
      #pragma unroll
      for (int s = 0; s < 4; s++) {
        sel_e[token * 4 + s] = keep[s] ? si[s] : -1;
        sel_w[token * 4 + s] = keep[s] ? sp[s] / wsum : 0.f;
      }
      #pragma unroll
      for (int e = 0; e < NE; e++) myp[e] += p[e];
      #pragma unroll
      for (int s = 0; s < 4; s++) if (keep[s]) myc[si[s]] += 1.f;
    }
  }
  if (lane == 0) {
    #pragma unroll
    for (int e = 0; e < NE; e++) { atomicAdd(&s_cnt[e], myc[e]); atomicAdd(&s_ps[e], myp[e]); }
  }
  __syncthreads();
  if (tid < NE) {
    part[blockIdx.x * 16 + tid] = s_cnt[tid];
    part[blockIdx.x * 16 + 8 + tid] = s_ps[tid];
  }
}

// ---------------- prep: aux scalar + expert bases (128-aligned) ----------------
__global__ void prep_kernel(const float* __restrict__ part, float* __restrict__ auxp,
                            int* __restrict__ meta) {
  __shared__ float red[16];
  int tid = threadIdx.x;
  if (tid < 16) {
    float s = 0.f;
    for (int b = 0; b < 256; b++) s += part[b * 16 + tid];
    red[tid] = s;
  }
  __syncthreads();
  if (tid == 0) {
    float tot = 0.f;
    for (int e = 0; e < NE; e++) tot += red[e];
    float t = fmaxf(tot, 1.f), s = 0.f;
    for (int e = 0; e < NE; e++) s += (red[e] / t) * (red[NE + e] / (float)NTOK);
    auxp[0] = 0.01f * (float)NE * s;
    int off = 0;
    for (int e = 0; e < NE; e++) {
      int c = (int)(red[e] + 0.5f);
      meta[e] = c; meta[8 + e] = off;
      off += (c + 127) & ~127;   // 128-granule padding (M-tile = 128)
    }
  }
  if (tid < NE) meta[16 + tid] = 0;
}

// ---------------- build compact assignment lists ----------------
__global__ __launch_bounds__(256) void build_kernel(const int* __restrict__ sel_e,
                                                    const float* __restrict__ sel_w,
                                                    int* __restrict__ meta,
                                                    int* __restrict__ mlist,
                                                    float* __restrict__ wrow,
                                                    int* __restrict__ arow) {
  __shared__ int lcnt[NE], roff[NE];
  int tid = threadIdx.x;
  if (tid < NE) lcnt[tid] = 0;
  __syncthreads();
  int t = blockIdx.x * 32 + tid;
  int slots[4], es[4];
  bool active = tid < 32;
  if (active) {
    #pragma unroll
    for (int s = 0; s < 4; s++) {
      es[s] = sel_e[t * 4 + s];
      slots[s] = (es[s] >= 0) ? atomicAdd(&lcnt[es[s]], 1) : -1;
    }
  }
  __syncthreads();
  if (tid < NE) roff[tid] = atomicAdd(&meta[16 + tid], lcnt[tid]);
  __syncthreads();
  if (active) {
    #pragma unroll
    for (int s = 0; s < 4; s++) {
      int e = es[s];
      if (e >= 0) {
        int hrow = meta[8 + e] + roff[e] + slots[s];
        mlist[hrow] = t;
        wrow[hrow] = sel_w[t * 4 + s];
        arow[t * 4 + s] = hrow;
      } else {
        arow[t * 4 + s] = -1;
      }
    }
  }
}

// ---------------- sparse GEMM1, 128x128 tile, BK=32, LDS double-buffered ----------------
// One barrier per K-iter; prefetch of tile k+1 issued right after the barrier,
// overlapping compute on tile k. Buffers: As/Bs x2 (8 KB each, 32 KB total).
__global__ __launch_bounds__(256) void gemm1_sp(const short* __restrict__ A,
                                                const short* __restrict__ W1t,
                                                const float* __restrict__ b1,
                                                short* __restrict__ H,
                                                const int* __restrict__ mlist,
                                                const int* __restrict__ meta) {
  __shared__ __align__(16) short As[2 * 128 * 32];
  __shared__ __align__(16) short Bs[2 * 128 * 32];
  int e = blockIdx.x >> 6, j = blockIdx.x & 63;
  int cnt = meta[e];
  if (j * 128 >= cnt) return;
  int base = meta[8 + e];
  int tid = threadIdx.x, wave = tid >> 6, lane = tid & 63;
  int wm = wave >> 1, wn = wave & 1, quad = lane >> 4, l16 = lane & 15;
  int n0 = blockIdx.y * 128;
  const short* Bt = W1t + (size_t)e * DFF * DM;

  // staging coords: chunk c = (g*4+wave)*64 + lane -> row c>>2, 16B seg c&3
  const short* ag[2]; const short* bg[2];
  #pragma unroll
  for (int g = 0; g < 2; g++) {
    int c = (g * 4 + wave) * 64 + lane;
    int row = c >> 2, seg = c & 3;
    int rl = j * 128 + row;
    int tok = mlist[base + (rl < cnt ? rl : cnt - 1)];
    ag[g] = A + (size_t)tok * DM + seg * 8;
    bg[g] = Bt + (size_t)(n0 + row) * DM + seg * 8;
  }

  f32x4 acc[4][4];
  #pragma unroll
  for (int i = 0; i < 4; i++)
    #pragma unroll
    for (int jj = 0; jj < 4; jj++) acc[i][jj] = (f32x4){0.f, 0.f, 0.f, 0.f};

  // prologue: stage tile 0 into buf 0
  #pragma unroll
  for (int g = 0; g < 2; g++) {
    GLD_LDS16(ag[g], As + (g * 4 + wave) * 512);
    GLD_LDS16(bg[g], Bs + (g * 4 + wave) * 512);
  }

  for (int kt = 0; kt < DM; kt += 32) {
    int cur = (kt >> 5) & 1;
    __syncthreads();               // drains vmcnt: buf cur ready; prev compute done
    if (kt + 32 < DM) {            // prefetch next tile into the other buffer
      int nb = (cur ^ 1) * 4096;
      #pragma unroll
      for (int g = 0; g < 2; g++) {
        GLD_LDS16(ag[g] + kt + 32, As + nb + (g * 4 + wave) * 512);
        GLD_LDS16(bg[g] + kt + 32, Bs + nb + (g * 4 + wave) * 512);
      }
    }
    const short* Ab = As + cur * 4096;
    const short* Bb = Bs + cur * 4096;
    bfrag afr[4], bfr[4];
    #pragma unroll
    for (int mi = 0; mi < 4; mi++)
      afr[mi] = *(const bfrag*)(Ab + (wm * 64 + mi * 16 + l16) * 32 + quad * 8);
    #pragma unroll
    for (int ni = 0; ni < 4; ni++)
      bfr[ni] = *(const bfrag*)(Bb + (wn * 64 + ni * 16 + l16) * 32 + quad * 8);
    #pragma unroll
    for (int mi = 0; mi < 4; mi++)
      #pragma unroll
      for (int ni = 0; ni < 4; ni++)
        acc[mi][ni] = __builtin_amdgcn_mfma_f32_16x16x32_bf16(afr[mi], bfr[ni], acc[mi][ni], 0, 0, 0);
  }
  const float* bb = b1 + (size_t)e * DFF;
  #pragma unroll
  for (int mi = 0; mi < 4; mi++) {
    int rbase = base + j * 128 + wm * 64 + mi * 16 + quad * 4;
    #pragma unroll
    for (int ni = 0; ni < 4; ni++) {
      int col = n0 + wn * 64 + ni * 16 + l16;
      float bv = bb[col];
      #pragma unroll
      for (int r = 0; r < 4; r++)
        H[(size_t)(rbase + r) * DFF + col] = f2bf(fast_gelu(acc[mi][ni][r] + bv));
    }
  }
}

// ---------------- sparse GEMM2, same dbuf structure, K=DFF ----------------
__global__ __launch_bounds__(256) void gemm2_sp(const short* __restrict__ H,
                                                const short* __restrict__ W2t,
                                                const float* __restrict__ b2,
                                                short* __restrict__ partial,
                                                const float* __restrict__ wrow,
                                                const int* __restrict__ meta) {
  __shared__ __align__(16) short As[2 * 128 * 32];
  __shared__ __align__(16) short Bs[2 * 128 * 32];
  int e = blockIdx.x >> 6, j = blockIdx.x & 63;
  int cnt = meta[e];
  if (j * 128 >= cnt) return;
  int base = meta[8 + e];
  int tid = threadIdx.x, wave = tid >> 6, lane = tid & 63;
  int wm = wave >> 1, wn = wave & 1, quad = lane >> 4, l16 = lane & 15;
  int n0 = blockIdx.y * 128;
  const short* Bt = W2t + (size_t)e * DM * DFF;

  const short* ag[2]; const short* bg[2];
  #pragma unroll
  for (int g = 0; g < 2; g++) {
    int c = (g * 4 + wave) * 64 + lane;
    int row = c >> 2, seg = c & 3;
    ag[g] = H + (size_t)(base + j * 128 + row) * DFF + seg * 8;
    bg[g] = Bt + (size_t)(n0 + row) * DFF + seg * 8;
  }

  f32x4 acc[4][4];
  #pragma unroll
  for (int i = 0; i < 4; i++)
    #pragma unroll
    for (int jj = 0; jj < 4; jj++) acc[i][jj] = (f32x4){0.f, 0.f, 0.f, 0.f};

  #pragma unroll
  for (int g = 0; g < 2; g++) {
    GLD_LDS16(ag[g], As + (g * 4 + wave) * 512);
    GLD_LDS16(bg[g], Bs + (g * 4 + wave) * 512);
  }

  for (int kt = 0; kt < DFF; kt += 32) {
    int cur = (kt >> 5) & 1;
    __syncthreads();
    if (kt + 32 < DFF) {
      int nb = (cur ^ 1) * 4096;
      #pragma unroll
      for (int g = 0; g < 2; g++) {
        GLD_LDS16(ag[g] + kt + 32, As + nb + (g * 4 + wave) * 512);
        GLD_LDS16(bg[g] + kt + 32, Bs + nb + (g * 4 + wave) * 512);
      }
    }
    const short* Ab = As + cur * 4096;
    const short* Bb = Bs + cur * 4096;
    bfrag afr[4], bfr[4];
    #pragma unroll
    for (int mi = 0; mi < 4; mi++)
      afr[mi] = *(const bfrag*)(Ab + (wm * 64 + mi * 16 + l16) * 32 + quad * 8);
    #pragma unroll
    for (int ni = 0; ni < 4; ni++)
      bfr[ni] = *(const bfrag*)(Bb + (wn * 64 + ni * 16 + l16) * 32 + quad * 8);
    #pragma unroll
    for (int mi = 0; mi < 4; mi++)
      #pragma unroll
      for (int ni = 0; ni < 4; ni++)
        acc[mi][ni] = __builtin_amdgcn_mfma_f32_16x16x32_bf16(afr[mi], bfr[ni], acc[mi][ni], 0, 0, 0);
  }
  const float* bb = b2 + (size_t)e * DM;
  #pragma unroll
  for (int mi = 0; mi < 4; mi++) {
    int rbase = base + j * 128 + wm * 64 + mi * 16 + quad * 4;
    #pragma unroll
    for (int ni = 0; ni < 4; ni++) {
      int col = n0 + wn * 64 + ni * 16 + l16;
      float bv = bb[col];
      #pragma unroll
      for (int r = 0; r < 4; r++) {
        float w = wrow[rbase + r];
        partial[(size_t)(rbase + r) * DM + col] = f2bf(w * (acc[mi][ni][r] + bv));
      }
    }
  }
}

// ---------------- combine ----------------
__global__ __launch_bounds__(256) void combine_kernel(const short* __restrict__ partial,
                                                      const int* __restrict__ arow,
                                                      float* __restrict__ out) {
  int gid = blockIdx.x * 256 + threadIdx.x;
  int t = gid >> 6, c0 = (gid & 63) << 3;
  const int* ar = arow + t * 4;
  float o[8];
  #pragma unroll
  for (int k = 0; k < 8; k++) o[k] = 0.f;
  #pragma unroll
  for (int s = 0; s < 4; s++) {
    int a = ar[s];
    if (a >= 0) {
      union { u32x4 v; short s16[8]; } buf;
      buf.v = *(const u32x4*)(partial + (size_t)a * DM + c0);
      #pragma unroll
      for (int k = 0; k < 8; k++) o[k] += bf2f(buf.s16[k]);
    }
  }
  float* op = out + (size_t)t * DM + c0;
  *(f32x4*)op = (f32x4){o[0], o[1], o[2], o[3]};
  *(f32x4*)(op + 4) = (f32x4){o[4], o[5], o[6], o[7]};
}

extern "C" void kernel_launch(void* const* d_in, const int* in_sizes, int n_in,
                              void* d_out, int out_size, void* d_ws, size_t ws_size,
                              hipStream_t stream) {
  const float* x  = (const float*)d_in[0];
  const float* rw = (const float*)d_in[1];
  const float* W1 = (const float*)d_in[2];
  const float* b1 = (const float*)d_in[3];
  const float* W2 = (const float*)d_in[4];
  const float* b2 = (const float*)d_in[5];
  float* out = (float*)d_out;

  char* base_p = (char*)d_ws; char* p = base_p;
  auto carve = [&](size_t bytes) { char* r = p; p += (bytes + 255) & ~(size_t)255; return r; };
  short* xb    = (short*)carve((size_t)NTOK * DM * 2);
  short* w1b   = (short*)carve((size_t)NE * DM * DFF * 2);  // [e][DFF][DM]
  short* w2b   = (short*)carve((size_t)NE * DFF * DM * 2);  // [e][DM][DFF]
  int*   sel_e = (int*)carve((size_t)NTOK * 4 * 4);
  float* sel_w = (float*)carve((size_t)NTOK * 4 * 4);
  float* part  = (float*)carve(256 * 16 * 4);
  int*   meta  = (int*)carve(64 * 4);
  int*   arow  = (int*)carve((size_t)NTOK * 4 * 4);
  int*   mlist = (int*)carve((size_t)ROWCAP * 4);
  float* wrow  = (float*)carve((size_t)ROWCAP * 4);
  short* Hbig  = (short*)carve((size_t)ROWCAP * DFF * 2);
  short* partial = (short*)carve((size_t)ROWCAP * DM * 2);

  cvt_kernel<<<(NTOK * DM / 4 + 255) / 256, 256, 0, stream>>>(x, xb, NTOK * DM / 4);
  cvtT_kernel<<<dim3(DM / 32, DFF / 32, NE), 256, 0, stream>>>(W1, w1b, DM, DFF);
  cvtT_kernel<<<dim3(DFF / 32, DM / 32, NE), 256, 0, stream>>>(W2, w2b, DFF, DM);
  router_kernel<<<256, 256, 0, stream>>>(x, rw, sel_e, sel_w, part);
  prep_kernel<<<1, 64, 0, stream>>>(part, out + (size_t)NTOK * DM, meta);
  build_kernel<<<256, 256, 0, stream>>>(sel_e, sel_w, meta, mlist, wrow, arow);
  gemm1_sp<<<dim3(NE * 64, DFF / 128), 256, 0, stream>>>(xb, w1b, b1, Hbig, mlist, meta);
  gemm2_sp<<<dim3(NE * 64, DM / 128), 256, 0, stream>>>(Hbig, w2b, b2, partial, wrow, meta);
  combine_kernel<<<NTOK * DM / 8 / 256, 256, 0, stream>>>(partial, arow, out);
}